// Round 8
// baseline (2478.539 us; speedup 1.0000x reference)
//
#include <hip/hip_runtime.h>
#include <hip/hip_bf16.h>

typedef __hip_bfloat16 bf16;
typedef __attribute__((ext_vector_type(8))) short bf16x8;
typedef __attribute__((ext_vector_type(4))) float f32x4;

#define GLDS16(g, l)                                                  \
  __builtin_amdgcn_global_load_lds(                                   \
      (const __attribute__((address_space(1))) void*)(g),             \
      (__attribute__((address_space(3))) void*)(l), 16, 0, 0)

__device__ __forceinline__ float bf2f(bf16 v) { return __bfloat162float(v); }
__device__ __forceinline__ short f2bf(float f) {
  bf16 b = __float2bfloat16(f);
  return *reinterpret_cast<short*>(&b);
}

// Proven agent-scope primitives (R6): the ONLY cross-block comm mechanism.
__device__ __forceinline__ unsigned long long ald64(const void* p) {
  return __hip_atomic_load((const unsigned long long*)p, __ATOMIC_RELAXED,
                           __HIP_MEMORY_SCOPE_AGENT);
}
__device__ __forceinline__ void ast32(void* p, unsigned v) {
  __hip_atomic_store((unsigned*)p, v, __ATOMIC_RELAXED,
                     __HIP_MEMORY_SCOPE_AGENT);
}
__device__ __forceinline__ unsigned ald32(const void* p) {
  return __hip_atomic_load((const unsigned*)p, __ATOMIC_RELAXED,
                           __HIP_MEMORY_SCOPE_AGENT);
}

// ---------------------------------------------------------------------------
// f32 -> bf16 linear conversion, 8 elems/thread
// ---------------------------------------------------------------------------
__global__ __launch_bounds__(256) void cvt_bf16(const float* __restrict__ in,
                                                bf16* __restrict__ out, int n) {
  const int i = (blockIdx.x * 256 + threadIdx.x) * 8;
  if (i >= n) return;
  const float4 u = *(const float4*)(in + i);
  const float4 v = *(const float4*)(in + i + 4);
  bf16x8 w;
  w[0] = f2bf(u.x); w[1] = f2bf(u.y); w[2] = f2bf(u.z); w[3] = f2bf(u.w);
  w[4] = f2bf(v.x); w[5] = f2bf(v.y); w[6] = f2bf(v.z); w[7] = f2bf(v.w);
  *(bf16x8*)(out + i) = w;
}

// ---------------------------------------------------------------------------
// Wh (f32, [3072][1024] per dir) -> bf16 in MFMA B-fragment order:
// Whb[dir][cg(64)][gate(3)][kk(32)][lane(64)][8]
// ---------------------------------------------------------------------------
__global__ __launch_bounds__(256) void cvt_whb(const float* __restrict__ Wh_f,
                                               const float* __restrict__ Wh_r,
                                               bf16* __restrict__ Whb) {
  const int t = blockIdx.x * 256 + threadIdx.x;  // 786432 threads
  const int d = t / 393216;
  int r = t % 393216;
  const int cg = r / 6144;  r %= 6144;
  const int g = r / 2048;   r %= 2048;
  const int kk = r / 64;
  const int lane = r & 63;
  const float* Wh = d ? Wh_r : Wh_f;
  const int row = g * 1024 + cg * 16 + (lane & 15);
  const int col = kk * 32 + (lane >> 4) * 8;
  const float* s = Wh + (size_t)row * 1024 + col;
  const float4 u = *(const float4*)s;
  const float4 v = *(const float4*)(s + 4);
  bf16x8 w;
  w[0] = f2bf(u.x); w[1] = f2bf(u.y); w[2] = f2bf(u.z); w[3] = f2bf(u.w);
  w[4] = f2bf(v.x); w[5] = f2bf(v.y); w[6] = f2bf(v.z); w[7] = f2bf(v.w);
  *(bf16x8*)(Whb + (size_t)t * 8) = w;
}

// ---------------------------------------------------------------------------
// Prologue: Gi[32768][3072] = Xb @ Wib^T + bi   (all bf16, m97-style GLDS)
// ---------------------------------------------------------------------------
__global__ __launch_bounds__(256) void gi_gemm(const bf16* __restrict__ X,
                                               const bf16* __restrict__ Wi,
                                               const float* __restrict__ bi,
                                               bf16* __restrict__ Gi) {
  __shared__ bf16 As[128 * 32];
  __shared__ bf16 Bs[128 * 32];
  const int tid = threadIdx.x;
  const int lane = tid & 63;
  const int w = tid >> 6;
  const int wm = w >> 1, wn = w & 1;
  const int m0 = blockIdx.y * 128;
  const int n0 = blockIdx.x * 128;
  const int rA = lane & 15;
  const int kl = (lane >> 4) * 8;

  f32x4 acc[4][4] = {};

  const bf16* Ab = X + (size_t)m0 * 1024;
  const bf16* Bb = Wi + (size_t)n0 * 1024;

  const int arow = tid >> 2;
  const int akk = (tid & 3) * 8;

  for (int kt = 0; kt < 1024; kt += 32) {
#pragma unroll
    for (int i = 0; i < 2; ++i) {
      GLDS16(Ab + (size_t)(i * 64 + arow) * 1024 + kt + akk,
             As + (i * 256 + w * 64) * 8);
      GLDS16(Bb + (size_t)(i * 64 + arow) * 1024 + kt + akk,
             Bs + (i * 256 + w * 64) * 8);
    }
    asm volatile("s_waitcnt vmcnt(0)" ::: "memory");
    __syncthreads();

    bf16x8 a[4], b[4];
#pragma unroll
    for (int f = 0; f < 4; ++f) {
      a[f] = *(const bf16x8*)(As + (wm * 64 + f * 16 + rA) * 32 + kl);
      b[f] = *(const bf16x8*)(Bs + (wn * 64 + f * 16 + rA) * 32 + kl);
    }
#pragma unroll
    for (int mf = 0; mf < 4; ++mf)
#pragma unroll
      for (int nf = 0; nf < 4; ++nf)
        acc[mf][nf] = __builtin_amdgcn_mfma_f32_16x16x32_bf16(
            a[mf], b[nf], acc[mf][nf], 0, 0, 0);
    __syncthreads();
  }

  const int rgrp = (lane >> 4) * 4;
#pragma unroll
  for (int nf = 0; nf < 4; ++nf) {
    const int col = n0 + wn * 64 + nf * 16 + rA;
    const float bv = bi[col];
#pragma unroll
    for (int mf = 0; mf < 4; ++mf) {
#pragma unroll
      for (int j = 0; j < 4; ++j) {
        const int row = m0 + wm * 64 + mf * 16 + rgrp + j;
        Gi[(size_t)row * 3072 + col] = __float2bfloat16(acc[mf][nf][j] + bv);
      }
    }
  }
}

// ---------------------------------------------------------------------------
// FAST path: 512 blocks x 128 threads (2 waves), 2 blocks/CU co-resident.
// Block = 32 rows x 16 cols; chain = bid&7 (8 chains x 64 blocks);
// 64-slot flag barrier (1 slot per lane of wave0). r,z B-frags register-
// resident (512-reg budget at 1 wave/EU); n gate streamed from warm L2.
// Launched ONLY if host occupancy query confirms >=2 blocks/CU.
// ---------------------------------------------------------------------------
__global__ __launch_bounds__(128, 1) void gru_persist_f(
    const bf16* __restrict__ Whb, const float* __restrict__ bh_f,
    const float* __restrict__ bh_r, const bf16* __restrict__ Gi,
    const float* __restrict__ mask, bf16* __restrict__ h16,
    unsigned* __restrict__ flags, float* __restrict__ out) {
  __shared__ bf16 hs[32 * 1024];
  const int tid = threadIdx.x;
  const int lane = tid & 63;
  const int w = tid >> 6;        // 0..1
  const int mg = w;
  const int bid = blockIdx.x;
  const int chain = bid & 7;
  const int ct = bid >> 3;       // 0..63 (16-col tiles)
  const int dir = chain >> 2;
  const int bt = chain & 3;
  unsigned* gflags = flags + chain * 128;

  const float* bh = dir ? bh_r : bh_f;
  const bf16* gi = Gi + (size_t)dir * (32768ull * 3072ull);
  const int bt0 = bt * 32;
  const int rA = lane & 15;
  const int klane = lane >> 4;
  const int row = mg * 16 + rA;
  const int colg = ct * 16 + rA;

  bf16* hbuf0 = h16 + (size_t)(dir * 2 + 0) * 131072;
  bf16* hbuf1 = h16 + (size_t)(dir * 2 + 1) * 131072;

  // r,z B-fragments resident (2 x 32 x 4 regs); n streamed
  const bf16* bp = Whb + (size_t)dir * 3145728 + (size_t)(ct * 3) * 16384 +
                   lane * 8;
  bf16x8 br[32], bz[32];
#pragma unroll
  for (int kk = 0; kk < 32; ++kk) br[kk] = *(const bf16x8*)(bp + kk * 512);
#pragma unroll
  for (int kk = 0; kk < 32; ++kk)
    bz[kk] = *(const bf16x8*)(bp + 16384 + kk * 512);
  const bf16* bpn = bp + 32768;

  const float bhr = bh[colg];
  const float bhz = bh[1024 + colg];
  const float bhn = bh[2048 + colg];

  float hp[4] = {0.f, 0.f, 0.f, 0.f};
  const int brow0 = bt0 + mg * 16 + klane * 4;

  float gir[4], giz[4], gin[4], mk4[4];
  {
    const int time0 = dir ? 255 : 0;
#pragma unroll
    for (int j = 0; j < 4; ++j) {
      const size_t gbase = ((size_t)(brow0 + j) * 256 + time0) * 3072 + colg;
      gir[j] = bf2f(gi[gbase]);
      giz[j] = bf2f(gi[gbase + 1024]);
      gin[j] = bf2f(gi[gbase + 2048]);
      mk4[j] = mask[(brow0 + j) * 256 + time0];
    }
  }

  for (int t = 0; t < 256; ++t) {
    const int time = dir ? (255 - t) : t;
    bf16* hin = (t & 1) ? hbuf1 : hbuf0;
    bf16* hout = (t & 1) ? hbuf0 : hbuf1;

    // ---- stage 64KB h tile: 64 x 8B agent loads/thread, 4 batches ----
#pragma unroll
    for (int b4 = 0; b4 < 4; ++b4) {
      unsigned long long vv[16];
#pragma unroll
      for (int q = 0; q < 16; ++q) {
        const int idx = (b4 * 16 + q) * 128 + tid;
        const int r = idx >> 8;
        const int c8 = idx & 255;
        vv[q] = ald64(hin + ((size_t)(bt0 + r) << 10) + c8 * 4);
      }
#pragma unroll
      for (int q = 0; q < 16; ++q) {
        const int idx = (b4 * 16 + q) * 128 + tid;
        const int r = idx >> 8;
        const int c8 = idx & 255;
        const int sw = (((c8 >> 1) ^ (r & 7)) << 4) | ((c8 & 1) << 3);
        *(unsigned long long*)((char*)hs + r * 2048 + sw) = vv[q];
      }
    }
    __syncthreads();

    // ---- gh = h @ Wh^T ----
    f32x4 acc0 = {}, acc1 = {}, acc2 = {};
#pragma unroll
    for (int kk = 0; kk < 32; ++kk) {
      const int cidx = kk * 4 + klane;
      bf16x8 a = *(const bf16x8*)(hs + row * 1024 + ((cidx ^ (row & 7)) << 3));
      bf16x8 bn = *(const bf16x8*)(bpn + kk * 512);
      acc0 = __builtin_amdgcn_mfma_f32_16x16x32_bf16(a, br[kk], acc0, 0, 0, 0);
      acc1 = __builtin_amdgcn_mfma_f32_16x16x32_bf16(a, bz[kk], acc1, 0, 0, 0);
      acc2 = __builtin_amdgcn_mfma_f32_16x16x32_bf16(a, bn, acc2, 0, 0, 0);
    }

    // ---- gates; h stores first (critical path) ----
    float hnv[4];
#pragma unroll
    for (int j = 0; j < 4; ++j) {
      const float gr = acc0[j] + bhr + gir[j];
      const float gz = acc1[j] + bhz + giz[j];
      const float ghn = acc2[j] + bhn;
      const float r = 1.f / (1.f + __expf(-gr));
      const float z = 1.f / (1.f + __expf(-gz));
      const float nin = gin[j] + r * ghn;
      const float n = 1.f - 2.f / (__expf(2.f * nin) + 1.f);  // tanh
      float hn = (1.f - z) * n + z * hp[j];
      hn = mk4[j] * hn + (1.f - mk4[j]) * hp[j];
      hp[j] = hn;
      hnv[j] = hn;
      const unsigned short hb = (unsigned short)f2bf(hn);
      const unsigned nb = (unsigned)__shfl_xor((int)hb, 1);
      if (!(lane & 1))
        ast32(hout + (((size_t)brow0 + j) << 10) + colg,
              (unsigned)hb | (nb << 16));
    }

    // ---- drain, signal own slot ----
    asm volatile("s_waitcnt vmcnt(0)" ::: "memory");
    __syncthreads();
    if (tid == 0) ast32(&gflags[ct], (unsigned)(t + 1));

    // ---- off-critical-path: out stores + next-step gi/mask prefetch ----
#pragma unroll
    for (int j = 0; j < 4; ++j)
      out[(((size_t)(brow0 + j)) * 256 + time) * 2048 + (size_t)(dir * 1024) +
          colg] = hnv[j];

    if (t < 255) {
      const int tn = dir ? (254 - t) : (t + 1);
#pragma unroll
      for (int j = 0; j < 4; ++j) {
        const size_t gbase = ((size_t)(brow0 + j) * 256 + tn) * 3072 + colg;
        gir[j] = bf2f(gi[gbase]);
        giz[j] = bf2f(gi[gbase + 1024]);
        gin[j] = bf2f(gi[gbase + 2048]);
        mk4[j] = mask[(brow0 + j) * 256 + tn];
      }
      if (w == 0) {  // 64 lanes poll 64 slots
        unsigned v;
        do {
          __builtin_amdgcn_s_sleep(1);
          v = ald32(&gflags[lane]);
        } while (__any((int)(v < (unsigned)(t + 1))));
      }
      __builtin_amdgcn_sched_barrier(0);
      __syncthreads();
    }
  }
}

// ---------------------------------------------------------------------------
// SAFE fallback: exact R6 structure (proven pass @2.43ms) + reorderings.
// Grid (32,4,2) x 256 threads, 32-slot barrier, r/z resident, n streamed.
// ---------------------------------------------------------------------------
__global__ __launch_bounds__(256, 1) void gru_persist_s(
    const bf16* __restrict__ Whb, const float* __restrict__ bh_f,
    const float* __restrict__ bh_r, const bf16* __restrict__ Gi,
    const float* __restrict__ mask, bf16* __restrict__ h16,
    unsigned* __restrict__ flags, float* __restrict__ out) {
  __shared__ bf16 hs[32 * 1024];
  const int tid = threadIdx.x;
  const int lane = tid & 63;
  const int w = tid >> 6;
  const int mg = w >> 1;
  const int cg = w & 1;
  const int ct = blockIdx.x;
  const int bt = blockIdx.y;
  const int dir = blockIdx.z;
  unsigned* gflags = flags + (dir * 4 + bt) * 128;

  const float* bh = dir ? bh_r : bh_f;
  const bf16* gi = Gi + (size_t)dir * (32768ull * 3072ull);
  const int bt0 = bt * 32;
  const int rA = lane & 15;
  const int klane = lane >> 4;
  const int row = mg * 16 + rA;
  const int colg = ct * 32 + cg * 16 + rA;

  bf16* hbuf0 = h16 + (size_t)(dir * 2 + 0) * 131072;
  bf16* hbuf1 = h16 + (size_t)(dir * 2 + 1) * 131072;

  const bf16* bp = Whb + (size_t)dir * 3145728 +
                   (size_t)((ct * 2 + cg) * 3) * 16384 + lane * 8;
  bf16x8 br[32], bz[32];
#pragma unroll
  for (int kk = 0; kk < 32; ++kk) br[kk] = *(const bf16x8*)(bp + kk * 512);
#pragma unroll
  for (int kk = 0; kk < 32; ++kk)
    bz[kk] = *(const bf16x8*)(bp + 16384 + kk * 512);
  const bf16* bpn = bp + 32768;

  const float bhr = bh[colg];
  const float bhz = bh[1024 + colg];
  const float bhn = bh[2048 + colg];

  float hp[4] = {0.f, 0.f, 0.f, 0.f};
  const int brow0 = bt0 + mg * 16 + klane * 4;

  float gir[4], giz[4], gin[4], mk4[4];
  {
    const int time0 = dir ? 255 : 0;
#pragma unroll
    for (int j = 0; j < 4; ++j) {
      const size_t gbase = ((size_t)(brow0 + j) * 256 + time0) * 3072 + colg;
      gir[j] = bf2f(gi[gbase]);
      giz[j] = bf2f(gi[gbase + 1024]);
      gin[j] = bf2f(gi[gbase + 2048]);
      mk4[j] = mask[(brow0 + j) * 256 + time0];
    }
  }

  for (int t = 0; t < 256; ++t) {
    const int time = dir ? (255 - t) : t;
    bf16* hin = (t & 1) ? hbuf1 : hbuf0;
    bf16* hout = (t & 1) ? hbuf0 : hbuf1;

#pragma unroll
    for (int half = 0; half < 2; ++half) {
      unsigned long long vv[16];
#pragma unroll
      for (int q = 0; q < 16; ++q) {
        const int idx = (half * 16 + q) * 256 + tid;
        const int r = idx >> 8;
        const int c8 = idx & 255;
        vv[q] = ald64(hin + ((size_t)(bt0 + r) << 10) + c8 * 4);
      }
#pragma unroll
      for (int q = 0; q < 16; ++q) {
        const int idx = (half * 16 + q) * 256 + tid;
        const int r = idx >> 8;
        const int c8 = idx & 255;
        const int sw = (((c8 >> 1) ^ (r & 7)) << 4) | ((c8 & 1) << 3);
        *(unsigned long long*)((char*)hs + r * 2048 + sw) = vv[q];
      }
    }
    __syncthreads();

    f32x4 acc0 = {}, acc1 = {}, acc2 = {};
#pragma unroll
    for (int kk = 0; kk < 32; ++kk) {
      const int cidx = kk * 4 + klane;
      bf16x8 a = *(const bf16x8*)(hs + row * 1024 + ((cidx ^ (row & 7)) << 3));
      bf16x8 bn = *(const bf16x8*)(bpn + kk * 512);
      acc0 = __builtin_amdgcn_mfma_f32_16x16x32_bf16(a, br[kk], acc0, 0, 0, 0);
      acc1 = __builtin_amdgcn_mfma_f32_16x16x32_bf16(a, bz[kk], acc1, 0, 0, 0);
      acc2 = __builtin_amdgcn_mfma_f32_16x16x32_bf16(a, bn, acc2, 0, 0, 0);
    }

    float hnv[4];
#pragma unroll
    for (int j = 0; j < 4; ++j) {
      const float gr = acc0[j] + bhr + gir[j];
      const float gz = acc1[j] + bhz + giz[j];
      const float ghn = acc2[j] + bhn;
      const float r = 1.f / (1.f + __expf(-gr));
      const float z = 1.f / (1.f + __expf(-gz));
      const float nin = gin[j] + r * ghn;
      const float n = 1.f - 2.f / (__expf(2.f * nin) + 1.f);
      float hn = (1.f - z) * n + z * hp[j];
      hn = mk4[j] * hn + (1.f - mk4[j]) * hp[j];
      hp[j] = hn;
      hnv[j] = hn;
      const unsigned short hb = (unsigned short)f2bf(hn);
      const unsigned nb = (unsigned)__shfl_xor((int)hb, 1);
      if (!(lane & 1))
        ast32(hout + (((size_t)brow0 + j) << 10) + colg,
              (unsigned)hb | (nb << 16));
    }

    asm volatile("s_waitcnt vmcnt(0)" ::: "memory");
    __syncthreads();
    if (tid == 0) ast32(&gflags[ct], (unsigned)(t + 1));

#pragma unroll
    for (int j = 0; j < 4; ++j)
      out[(((size_t)(brow0 + j)) * 256 + time) * 2048 + (size_t)(dir * 1024) +
          colg] = hnv[j];

    if (t < 255) {
      const int tn = dir ? (254 - t) : (t + 1);
#pragma unroll
      for (int j = 0; j < 4; ++j) {
        const size_t gbase = ((size_t)(brow0 + j) * 256 + tn) * 3072 + colg;
        gir[j] = bf2f(gi[gbase]);
        giz[j] = bf2f(gi[gbase + 1024]);
        gin[j] = bf2f(gi[gbase + 2048]);
        mk4[j] = mask[(brow0 + j) * 256 + tn];
      }
      if (w == 0) {
        unsigned v;
        do {
          __builtin_amdgcn_s_sleep(1);
          v = ald32(&gflags[lane & 31]);
        } while (__any((int)(v < (unsigned)(t + 1))));
      }
      __builtin_amdgcn_sched_barrier(0);
      __syncthreads();
    }
  }
}

// ---------------------------------------------------------------------------
extern "C" void kernel_launch(void* const* d_in, const int* in_sizes, int n_in,
                              void* d_out, int out_size, void* d_ws,
                              size_t ws_size, hipStream_t stream) {
  const float* x = (const float*)d_in[0];
  const float* mask = (const float*)d_in[1];
  const float* Wi_f = (const float*)d_in[2];
  const float* Wh_f = (const float*)d_in[3];
  const float* bi_f = (const float*)d_in[4];
  const float* bh_f = (const float*)d_in[5];
  const float* Wi_r = (const float*)d_in[6];
  const float* Wh_r = (const float*)d_in[7];
  const float* bi_r = (const float*)d_in[8];
  const float* bh_r = (const float*)d_in[9];
  float* out = (float*)d_out;

  char* ws = (char*)d_ws;
  const size_t GI_ELEMS = 32768ull * 3072ull;  // per dir
  bf16* Gi = (bf16*)ws;                                   // 402.7 MB
  bf16* Whb = (bf16*)(ws + 2 * GI_ELEMS * sizeof(bf16));  // 12.6 MB
  bf16* h16 = Whb + 2 * 3145728;                          // 1 MB ping-pong
  unsigned* flags = (unsigned*)((char*)h16 + 1048576);    // 4 KB (8x512B)

  // bf16 X / Wi scratch lives in d_out (fully overwritten afterwards)
  bf16* Xb = (bf16*)d_out;
  bf16* Wib_f = Xb + 33554432;
  bf16* Wib_r = Wib_f + 3145728;

  hipMemsetAsync(h16, 0, 1048576 + 4096, stream);

  cvt_bf16<<<16384, 256, 0, stream>>>(x, Xb, 33554432);
  cvt_bf16<<<1536, 256, 0, stream>>>(Wi_f, Wib_f, 3145728);
  cvt_bf16<<<1536, 256, 0, stream>>>(Wi_r, Wib_r, 3145728);
  cvt_whb<<<3072, 256, 0, stream>>>(Wh_f, Wh_r, Whb);

  gi_gemm<<<dim3(24, 256), 256, 0, stream>>>(Xb, Wib_f, bi_f, Gi);
  gi_gemm<<<dim3(24, 256), 256, 0, stream>>>(Xb, Wib_r, bi_r, Gi + GI_ELEMS);

  // Deadlock guard: fast path needs all 512 blocks co-resident (2/CU).
  int occ = 0;
  (void)hipOccupancyMaxActiveBlocksPerMultiprocessor(&occ, gru_persist_f, 128,
                                                     0);
  if (occ >= 2)
    gru_persist_f<<<dim3(512), 128, 0, stream>>>(Whb, bh_f, bh_r, Gi, mask,
                                                 h16, flags, out);
  else
    gru_persist_s<<<dim3(32, 4, 2), 256, 0, stream>>>(Whb, bh_f, bh_r, Gi,
                                                      mask, h16, flags, out);
}